// Round 16
// baseline (98.615 us; speedup 1.0000x reference)
//
#include <hip/hip_runtime.h>

#define ALPHA 0.2f
#define BATCH 8
#define NN    2048
#define FD    256
// hT layout: [b][t=m/32][o=0..255][mj=0..31], short. 8192 shorts (16KB) per tile.
#define TILE_SH 8192
#define BSLAB   (FD*NN)          // shorts per batch slab (1 MB)

typedef __attribute__((ext_vector_type(8))) short short8;
typedef __attribute__((ext_vector_type(4))) float f32x4;
typedef __attribute__((ext_vector_type(4))) int   i32x4;

__device__ __forceinline__ unsigned short f2bf(float f){
  unsigned u = __builtin_bit_cast(unsigned, f);
  return (unsigned short)((u + 0x7FFFu + ((u>>16)&1u)) >> 16);   // RTN-even
}
__device__ __forceinline__ float dot4(float4 a, float4 b){
  return a.x*b.x + a.y*b.y + a.z*b.z + a.w*b.w;
}
// async global->LDS, 16B/lane: dest = uniform base + lane*16; src is per-lane.
__device__ __forceinline__ void gll16(const void* g, void* l){
  __builtin_amdgcn_global_load_lds(
      (const __attribute__((address_space(1))) unsigned int*)g,
      (__attribute__((address_space(3))) unsigned int*)l, 16, 0, 0);
}

// ---------------------------------------------------------------------------
// K0: w_src = W @ a_src, w_dst = W @ a_dst (exact fp32), WT[o][k] = bf16(W[k][o])
// ---------------------------------------------------------------------------
__global__ __launch_bounds__(64) void prep_w(
    const float* __restrict__ W, const float* __restrict__ a,
    float* __restrict__ w_src, float* __restrict__ w_dst,
    unsigned short* __restrict__ WT)
{
  const int k = blockIdx.x;
  const int l = threadIdx.x;
  float4 wv = *(const float4*)(W + k*FD + l*4);
  float4 as = *(const float4*)(a + l*4);
  float4 ad = *(const float4*)(a + FD + l*4);
  float s = dot4(wv, as);
  float d = dot4(wv, ad);
#pragma unroll
  for (int m=1;m<64;m<<=1){ s += __shfl_xor(s, m); d += __shfl_xor(d, m); }
  if (l == 0){ w_src[k] = s; w_dst[k] = d; }
  WT[(l*4+0)*FD + k] = f2bf(wv.x);
  WT[(l*4+1)*FD + k] = f2bf(wv.y);
  WT[(l*4+2)*FD + k] = f2bf(wv.z);
  WT[(l*4+3)*FD + k] = f2bf(wv.w);
}

// ---------------------------------------------------------------------------
// K1 (fused prep_x + gemm_h): 64-row XCD-affine blocks (grid 256), now with
// 512 threads = 8 waves, o-SPLIT (wave w owns WT cols [32w, 32w+32), 2 C-frags)
// — identical traffic to the R12 4-wave version (x rows L1-shared, WT read
// once/block), 2x the waves/SIMD for latency hiding. e-dot accumulation
// order unchanged -> bit-identical e; wave 0 writes.
// ---------------------------------------------------------------------------
__global__ __launch_bounds__(512) void gemm_he(
    const float* __restrict__ x,
    const float* __restrict__ w_src, const float* __restrict__ w_dst,
    const unsigned short* __restrict__ WT,
    unsigned short* __restrict__ hT,
    float* __restrict__ e_src, float* __restrict__ e_dst)
{
  const int tid = threadIdx.x;
  const int w = tid >> 6, l = tid & 63;     // w in [0,8)
  const int r16 = l & 15, g = l >> 4;
  const int b  = blockIdx.x & 7;
  const int nl = (blockIdx.x >> 3) << 6;      // 64 local rows
  const int row0 = b*NN + nl;

  f32x4 acc[4][2];                            // [row-group][cl]
#pragma unroll
  for (int gp=0;gp<4;gp++)
#pragma unroll
    for (int c=0;c<2;c++) acc[gp][c] = (f32x4){0.f,0.f,0.f,0.f};
  float esp[4] = {0.f,0.f,0.f,0.f};
  float edp[4] = {0.f,0.f,0.f,0.f};

  const float* xbase = x + (size_t)(row0 + r16)*FD + g*8;
  const unsigned short* wbase = WT + (size_t)(w*32 + r16)*FD + g*8;
#pragma unroll
  for (int s=0;s<8;s++){
    int4 bfr[2];
#pragma unroll
    for (int cl=0;cl<2;cl++)
      bfr[cl] = *(const int4*)(wbase + (size_t)cl*16*FD + s*32);
    float4 ws0 = *(const float4*)(w_src + s*32 + g*8);
    float4 ws1 = *(const float4*)(w_src + s*32 + g*8 + 4);
    float4 wd0 = *(const float4*)(w_dst + s*32 + g*8);
    float4 wd1 = *(const float4*)(w_dst + s*32 + g*8 + 4);
#pragma unroll
    for (int gp=0;gp<4;gp++){
      float4 x0 = *(const float4*)(xbase + (size_t)gp*16*FD + s*32);
      float4 x1 = *(const float4*)(xbase + (size_t)gp*16*FD + s*32 + 4);
      esp[gp] += dot4(x0,ws0) + dot4(x1,ws1);
      edp[gp] += dot4(x0,wd0) + dot4(x1,wd1);
      union { short8 v; unsigned short u[8]; } A;
      A.u[0]=f2bf(x0.x); A.u[1]=f2bf(x0.y); A.u[2]=f2bf(x0.z); A.u[3]=f2bf(x0.w);
      A.u[4]=f2bf(x1.x); A.u[5]=f2bf(x1.y); A.u[6]=f2bf(x1.z); A.u[7]=f2bf(x1.w);
#pragma unroll
      for (int cl=0;cl<2;cl++)
        acc[gp][cl] = __builtin_amdgcn_mfma_f32_16x16x32_bf16(
            A.v, __builtin_bit_cast(short8, bfr[cl]), acc[gp][cl], 0, 0, 0);
    }
  }
  // ---- e reduce + write by wave 0 (identical accumulation order to R12) ----
#pragma unroll
  for (int gp=0;gp<4;gp++){
    float es_ = esp[gp], ed_ = edp[gp];
    es_ += __shfl_xor(es_, 16); es_ += __shfl_xor(es_, 32);
    ed_ += __shfl_xor(ed_, 16); ed_ += __shfl_xor(ed_, 32);
    if (w == 0 && l < 16){
      e_src[row0 + gp*16 + l] = es_;
      e_dst[row0 + gp*16 + l] = ed_;
    }
  }
  // ---- hT write (fragment-linear tiled) ----
#pragma unroll
  for (int gp=0;gp<4;gp++){
    const int rl  = nl + gp*16;               // local row base
    const int t   = rl >> 5;                  // m-tile of 32
    const int mj  = ((rl >> 4) & 1) * 16 + g*4;
    unsigned short* dst = hT + (size_t)b*BSLAB + (size_t)t*TILE_SH + mj;
#pragma unroll
    for (int cl=0;cl<2;cl++){
      const int o = w*32 + cl*16 + r16;
      uint2 u;
      u.x = (unsigned)f2bf(acc[gp][cl][0]) | ((unsigned)f2bf(acc[gp][cl][1])<<16);
      u.y = (unsigned)f2bf(acc[gp][cl][2]) | ((unsigned)f2bf(acc[gp][cl][3])<<16);
      *(uint2*)(dst + o*32) = u;
    }
  }
}

// ---------------------------------------------------------------------------
// K2: fused scores + exp + PV + normalize + ELU.  VERBATIM R12 (best: 68.2us)
// — two barriers/step, counted vmcnt(8), depth-1 adj/e prefetch, XOR swizzle,
// setprio around MFMA, 2-round epilogue.
// ---------------------------------------------------------------------------
__global__ __launch_bounds__(512,2) void gat_fused(
    const int* __restrict__ adj,
    const float* __restrict__ e_src,
    const float* __restrict__ e_dst,
    const unsigned short* __restrict__ hT,
    float* __restrict__ out)
{
  __shared__ __align__(16) char smem[131072];     // 2 buf x 4 q-tiles x 16 KB
  __shared__ float rsum[4][4][16];                // [tile][q][16]

  const int tid = threadIdx.x;
  const int Wv  = tid >> 6;
  const int q   = Wv & 3;              // m-quarter
  const int w   = Wv >> 2;             // n-pair
  const int l   = tid & 63;
  const int r16 = l & 15, g = l >> 4;
  const int b   = blockIdx.x & 7;      // XCD-affine batch
  const int n0  = (blockIdx.x >> 3) << 6;        // 64 rows/block

  const int* adjR0 = adj + (size_t)(b*NN + n0 + w*32 + r16)*NN + q*512 + g*8;
  const int* adjR1 = adjR0 + (size_t)16*NN;
  const float* edB = e_dst + b*NN + q*512 + g*8;
  // gll source: lane byte-offset pre-swizzled (involution on bits 4-5)
  const int lsw = ((l*16) ^ (((l>>3)&3)<<4)) >> 1;   // in shorts
  const unsigned short* hTq = hT + (size_t)b*BSLAB + (size_t)q*16*TILE_SH
                                 + (size_t)w*4096 + lsw;
  char* ldsW       = smem + q*16384 + w*8192;    // stage dest (+buf*65536+i*1024)
  const char* ldsR = smem + q*16384;             // read base (+buf*65536)
  // swizzled B-frag read offset within a 1KB o-subtile
  const int hoff = (r16*64 + g*16) ^ (((r16>>1)&3)<<4);
  const float es0 = e_src[b*NN + n0 + w*32 + r16];
  const float es1 = e_src[b*NN + n0 + w*32 + 16 + r16];

  f32x4 acc0[16], acc1[16];
#pragma unroll
  for (int c=0;c<16;c++){ acc0[c] = (f32x4){0.f,0.f,0.f,0.f};
                          acc1[c] = (f32x4){0.f,0.f,0.f,0.f}; }
  float ps0 = 0.f, ps1 = 0.f;

  auto mkp = [&](i32x4 a0, i32x4 a1, float4 e0, float4 e1,
                 float es, float& ps)->short8{
    int   ai[8] = {a0[0],a0[1],a0[2],a0[3],a1[0],a1[1],a1[2],a1[3]};
    float ev[8] = {e0.x,e0.y,e0.z,e0.w,e1.x,e1.y,e1.z,e1.w};
    unsigned pt[8];
#pragma unroll
    for (int j=0;j<8;j++){
      float s = es + ev[j];
      s = fmaxf(s, ALPHA*s);                       // leaky relu
      float p = __expf(s);
      p = (ai[j] > 0) ? p : 0.f;
      unsigned ub = __builtin_bit_cast(unsigned, p) & 0xFFFF0000u;
      ps += __builtin_bit_cast(float, ub);         // rowsum of truncated P
      pt[j] = ub;
    }
    union { short8 v; unsigned u[4]; } A;
#pragma unroll
    for (int j=0;j<4;j++) A.u[j] = pt[2*j+1] | (pt[2*j] >> 16);
    return A.v;
  };

  // ---- prologue: adj(0), e(0), stage tile 0 -> buf0 ----
  i32x4 aj00,aj01, aj10,aj11;
  float4 eC0, eC1;
  {
    const i32x4* p0 = (const i32x4*)adjR0;
    aj00 = __builtin_nontemporal_load(p0);
    aj01 = __builtin_nontemporal_load(p0+1);
    const i32x4* p1 = (const i32x4*)adjR1;
    aj10 = __builtin_nontemporal_load(p1);
    aj11 = __builtin_nontemporal_load(p1+1);
    eC0 = *(const float4*)edB; eC1 = *(const float4*)(edB+4);
  }
#pragma unroll
  for (int i=0;i<8;i++) gll16(hTq + i*512, ldsW + i*1024);

  for (int t = 0; t < 16; ++t){
    const int cur = t & 1, nxt = cur ^ 1;
    const int ts  = (t < 15) ? t+1 : 15;           // stage target (tail dummy)
    // (1) stage tile ts into buf[nxt] : 8 gll16
    {
      const unsigned short* gsrc = hTq + (size_t)ts*TILE_SH;
      char* ld = ldsW + nxt*65536;
#pragma unroll
      for (int i=0;i<8;i++) gll16(gsrc + i*512, ld + i*1024);
    }
    // (2) wait: everything older than this step's 8 gll retired.
    asm volatile("s_waitcnt vmcnt(8)" ::: "memory");
    __builtin_amdgcn_sched_barrier(0);
    __builtin_amdgcn_s_barrier();
    __builtin_amdgcn_sched_barrier(0);
    // (3) softmax fragments for step t (adj/e in regs)
    short8 pa0 = mkp(aj00,aj01, eC0,eC1, es0, ps0);
    short8 pa1 = mkp(aj10,aj11, eC0,eC1, es1, ps1);
    // (4) refill adj/e for t+1 (fly across the end barrier)
    const int tn = (t < 15) ? t+1 : 0;
    {
      const i32x4* p0 = (const i32x4*)(adjR0 + tn*32);
      aj00 = __builtin_nontemporal_load(p0);
      aj01 = __builtin_nontemporal_load(p0+1);
      const i32x4* p1 = (const i32x4*)(adjR1 + tn*32);
      aj10 = __builtin_nontemporal_load(p1);
      aj11 = __builtin_nontemporal_load(p1+1);
      const float* ep = edB + tn*32;
      eC0 = *(const float4*)ep; eC1 = *(const float4*)(ep+4);
    }
    // (5) ds_read (swizzled) + MFMA
    {
      const char* rb = ldsR + cur*65536;
      __builtin_amdgcn_s_setprio(1);
#pragma unroll
      for (int c=0;c<16;c++){
        int4 bv = *(const int4*)(rb + c*1024 + hoff);
        acc0[c] = __builtin_amdgcn_mfma_f32_16x16x32_bf16(
                    pa0, __builtin_bit_cast(short8, bv), acc0[c], 0, 0, 0);
        acc1[c] = __builtin_amdgcn_mfma_f32_16x16x32_bf16(
                    pa1, __builtin_bit_cast(short8, bv), acc1[c], 0, 0, 0);
      }
      __builtin_amdgcn_s_setprio(0);
    }
    // (6) end barrier: protects buf[cur] from next step's staging (WAR)
    __builtin_amdgcn_sched_barrier(0);
    __builtin_amdgcn_s_barrier();
    __builtin_amdgcn_sched_barrier(0);
  }
  asm volatile("" :: "v"(aj00[0]),"v"(aj10[0]),"v"(eC0.x),"v"(eC1.x));

  // ---- partial rowsums ----
  float rs0 = ps0, rs1 = ps1;
  rs0 += __shfl_xor(rs0, 16); rs0 += __shfl_xor(rs0, 32);
  rs1 += __shfl_xor(rs1, 16); rs1 += __shfl_xor(rs1, 32);
  if (l < 16){ rsum[w*2][q][l] = rs0; rsum[w*2+1][q][l] = rs1; }
  __syncthreads();

  float t0 = rsum[w*2  ][0][r16] + rsum[w*2  ][1][r16]
           + rsum[w*2  ][2][r16] + rsum[w*2  ][3][r16];
  float t1 = rsum[w*2+1][0][r16] + rsum[w*2+1][1][r16]
           + rsum[w*2+1][2][r16] + rsum[w*2+1][3][r16];
  float inv0[4], inv1[4];
#pragma unroll
  for (int r=0;r<4;r++){ inv0[r] = 1.0f / __shfl(t0, g*4 + r);
                         inv1[r] = 1.0f / __shfl(t1, g*4 + r); }

  // ---- 2 combine rounds (full tile per round), red on staging LDS ----
  f32x4* red = (f32x4*)smem;                       // [w][c16][q][l]
#define RED(W_,C_,Q_,L_) red[(((W_)*16 + (C_))*4 + (Q_))*64 + (L_)]
#pragma unroll
  for (int s = 0; s < 2; ++s){
    f32x4* accp = s ? acc1 : acc0;
#pragma unroll
    for (int c=0;c<16;c++) RED(w,c,q,l) = accp[c];
    __syncthreads();
    const float* inv_ = s ? inv1 : inv0;
    float* outB = out + (size_t)(b*NN + n0 + w*32 + s*16)*FD;
#pragma unroll
    for (int i=0;i<4;i++){
      const int c = q*4 + i;
      f32x4 v = RED(w,c,0,l) + RED(w,c,1,l) + RED(w,c,2,l) + RED(w,c,3,l);
#pragma unroll
      for (int r=0;r<4;r++){
        float o = v[r] * inv_[r];
        o = o > 0.f ? o : (__expf(o) - 1.f);       // ELU
        __builtin_nontemporal_store(o,
            &outB[(size_t)(g*4 + r)*FD + c*16 + r16]);
      }
    }
    __syncthreads();
  }
#undef RED
}

// ---------------------------------------------------------------------------
extern "C" void kernel_launch(void* const* d_in, const int* in_sizes, int n_in,
                              void* d_out, int out_size, void* d_ws, size_t ws_size,
                              hipStream_t stream)
{
  const float* x   = (const float*)d_in[0];
  const int*   adj = (const int*)  d_in[1];
  const float* W   = (const float*)d_in[2];
  const float* a   = (const float*)d_in[3];
  float* out = (float*)d_out;

  char* ws = (char*)d_ws;
  size_t off = 0;
  auto alloc = [&](size_t bytes)->char*{
    char* p = ws + off; off += (bytes + 255) & ~(size_t)255; return p;
  };
  unsigned short* WT    = (unsigned short*)alloc((size_t)FD*FD*2);
  float*          w_src = (float*)alloc(FD*4);
  float*          w_dst = (float*)alloc(FD*4);
  float*          e_src = (float*)alloc((size_t)BATCH*NN*4);
  float*          e_dst = (float*)alloc((size_t)BATCH*NN*4);
  unsigned short* hT    = (unsigned short*)alloc((size_t)BATCH*NN*FD*2);

  prep_w   <<<FD,              64,  0, stream>>>(W, a, w_src, w_dst, WT);
  gemm_he  <<<(BATCH*NN)/64,   512, 0, stream>>>(x, w_src, w_dst, WT, hT, e_src, e_dst);
  gat_fused<<<(BATCH*NN)/64,   512, 0, stream>>>(adj, e_src, e_dst, hT, out);
}

// Round 17
// 68.136 us; speedup vs baseline: 1.4473x; 1.4473x over previous
//
#include <hip/hip_runtime.h>

#define ALPHA 0.2f
#define BATCH 8
#define NN    2048
#define FD    256
// hT layout: [b][t=m/32][o=0..255][mj=0..31], short. 8192 shorts (16KB) per tile.
#define TILE_SH 8192
#define BSLAB   (FD*NN)          // shorts per batch slab (1 MB)

typedef __attribute__((ext_vector_type(8))) short short8;
typedef __attribute__((ext_vector_type(4))) float f32x4;
typedef __attribute__((ext_vector_type(4))) int   i32x4;

__device__ __forceinline__ unsigned short f2bf(float f){
  unsigned u = __builtin_bit_cast(unsigned, f);
  return (unsigned short)((u + 0x7FFFu + ((u>>16)&1u)) >> 16);   // RTN-even
}
__device__ __forceinline__ float dot4(float4 a, float4 b){
  return a.x*b.x + a.y*b.y + a.z*b.z + a.w*b.w;
}
// async global->LDS, 16B/lane: dest = uniform base + lane*16; src is per-lane.
__device__ __forceinline__ void gll16(const void* g, void* l){
  __builtin_amdgcn_global_load_lds(
      (const __attribute__((address_space(1))) unsigned int*)g,
      (__attribute__((address_space(3))) unsigned int*)l, 16, 0, 0);
}

// ---------------------------------------------------------------------------
// K0: w_src = W @ a_src, w_dst = W @ a_dst (exact fp32), WT[o][k] = bf16(W[k][o])
// ---------------------------------------------------------------------------
__global__ __launch_bounds__(64) void prep_w(
    const float* __restrict__ W, const float* __restrict__ a,
    float* __restrict__ w_src, float* __restrict__ w_dst,
    unsigned short* __restrict__ WT)
{
  const int k = blockIdx.x;
  const int l = threadIdx.x;
  float4 wv = *(const float4*)(W + k*FD + l*4);
  float4 as = *(const float4*)(a + l*4);
  float4 ad = *(const float4*)(a + FD + l*4);
  float s = dot4(wv, as);
  float d = dot4(wv, ad);
#pragma unroll
  for (int m=1;m<64;m<<=1){ s += __shfl_xor(s, m); d += __shfl_xor(d, m); }
  if (l == 0){ w_src[k] = s; w_dst[k] = d; }
  WT[(l*4+0)*FD + k] = f2bf(wv.x);
  WT[(l*4+1)*FD + k] = f2bf(wv.y);
  WT[(l*4+2)*FD + k] = f2bf(wv.z);
  WT[(l*4+3)*FD + k] = f2bf(wv.w);
}

// ---------------------------------------------------------------------------
// K1 (fused prep_x + gemm_h): R12's 64-row XCD-affine blocks (grid 256,
// 256 threads = 4 waves c-split). Reads x fp32 once; produces hT (bf16
// fragment-linear) + e_src/e_dst fp32. [R13 grid-1024: -10us (WT re-read);
// R16 512-thread o-split: -30us (x misses L1). This version is the optimum.]
// ---------------------------------------------------------------------------
__global__ __launch_bounds__(256) void gemm_he(
    const float* __restrict__ x,
    const float* __restrict__ w_src, const float* __restrict__ w_dst,
    const unsigned short* __restrict__ WT,
    unsigned short* __restrict__ hT,
    float* __restrict__ e_src, float* __restrict__ e_dst)
{
  const int tid = threadIdx.x;
  const int w = tid >> 6, l = tid & 63;
  const int r16 = l & 15, g = l >> 4;
  const int b  = blockIdx.x & 7;
  const int nl = (blockIdx.x >> 3) << 6;      // 64 local rows
  const int row0 = b*NN + nl;

  f32x4 acc[4][4];                            // [row-group][cl]
#pragma unroll
  for (int gp=0;gp<4;gp++)
#pragma unroll
    for (int c=0;c<4;c++) acc[gp][c] = (f32x4){0.f,0.f,0.f,0.f};
  float esp[4] = {0.f,0.f,0.f,0.f};
  float edp[4] = {0.f,0.f,0.f,0.f};

  const float* xbase = x + (size_t)(row0 + r16)*FD + g*8;
  const unsigned short* wbase = WT + (size_t)(w*64 + r16)*FD + g*8;
#pragma unroll
  for (int s=0;s<8;s++){
    int4 bfr[4];
#pragma unroll
    for (int cl=0;cl<4;cl++)
      bfr[cl] = *(const int4*)(wbase + (size_t)cl*16*FD + s*32);
    float4 ws0 = *(const float4*)(w_src + s*32 + g*8);
    float4 ws1 = *(const float4*)(w_src + s*32 + g*8 + 4);
    float4 wd0 = *(const float4*)(w_dst + s*32 + g*8);
    float4 wd1 = *(const float4*)(w_dst + s*32 + g*8 + 4);
#pragma unroll
    for (int gp=0;gp<4;gp++){
      float4 x0 = *(const float4*)(xbase + (size_t)gp*16*FD + s*32);
      float4 x1 = *(const float4*)(xbase + (size_t)gp*16*FD + s*32 + 4);
      esp[gp] += dot4(x0,ws0) + dot4(x1,ws1);
      edp[gp] += dot4(x0,wd0) + dot4(x1,wd1);
      union { short8 v; unsigned short u[8]; } A;
      A.u[0]=f2bf(x0.x); A.u[1]=f2bf(x0.y); A.u[2]=f2bf(x0.z); A.u[3]=f2bf(x0.w);
      A.u[4]=f2bf(x1.x); A.u[5]=f2bf(x1.y); A.u[6]=f2bf(x1.z); A.u[7]=f2bf(x1.w);
#pragma unroll
      for (int cl=0;cl<4;cl++)
        acc[gp][cl] = __builtin_amdgcn_mfma_f32_16x16x32_bf16(
            A.v, __builtin_bit_cast(short8, bfr[cl]), acc[gp][cl], 0, 0, 0);
    }
  }
  // ---- e reduce + write by wave 0 ----
#pragma unroll
  for (int gp=0;gp<4;gp++){
    float es_ = esp[gp], ed_ = edp[gp];
    es_ += __shfl_xor(es_, 16); es_ += __shfl_xor(es_, 32);
    ed_ += __shfl_xor(ed_, 16); ed_ += __shfl_xor(ed_, 32);
    if (w == 0 && l < 16){
      e_src[row0 + gp*16 + l] = es_;
      e_dst[row0 + gp*16 + l] = ed_;
    }
  }
  // ---- hT write (fragment-linear tiled) ----
#pragma unroll
  for (int gp=0;gp<4;gp++){
    const int rl  = nl + gp*16;               // local row base
    const int t   = rl >> 5;                  // m-tile of 32
    const int mj  = ((rl >> 4) & 1) * 16 + g*4;
    unsigned short* dst = hT + (size_t)b*BSLAB + (size_t)t*TILE_SH + mj;
#pragma unroll
    for (int cl=0;cl<4;cl++){
      const int o = w*64 + cl*16 + r16;
      uint2 u;
      u.x = (unsigned)f2bf(acc[gp][cl][0]) | ((unsigned)f2bf(acc[gp][cl][1])<<16);
      u.y = (unsigned)f2bf(acc[gp][cl][2]) | ((unsigned)f2bf(acc[gp][cl][3])<<16);
      *(uint2*)(dst + o*32) = u;
    }
  }
}

// ---------------------------------------------------------------------------
// K2: fused scores + exp + PV + normalize + ELU.  VERBATIM R12 (best: 68.2us)
// — two barriers/step, counted vmcnt(8), depth-1 adj/e prefetch, XOR swizzle,
// setprio around MFMA, 2-round epilogue. [Failed perturbations: single-barrier
// (-12us: syncthreads drains vmcnt(0) and exposes HBM tail), depth-2 A/B regs
// (-96us: scratch spill), no-swizzle (= within noise).]
// ---------------------------------------------------------------------------
__global__ __launch_bounds__(512,2) void gat_fused(
    const int* __restrict__ adj,
    const float* __restrict__ e_src,
    const float* __restrict__ e_dst,
    const unsigned short* __restrict__ hT,
    float* __restrict__ out)
{
  __shared__ __align__(16) char smem[131072];     // 2 buf x 4 q-tiles x 16 KB
  __shared__ float rsum[4][4][16];                // [tile][q][16]

  const int tid = threadIdx.x;
  const int Wv  = tid >> 6;
  const int q   = Wv & 3;              // m-quarter
  const int w   = Wv >> 2;             // n-pair
  const int l   = tid & 63;
  const int r16 = l & 15, g = l >> 4;
  const int b   = blockIdx.x & 7;      // XCD-affine batch
  const int n0  = (blockIdx.x >> 3) << 6;        // 64 rows/block

  const int* adjR0 = adj + (size_t)(b*NN + n0 + w*32 + r16)*NN + q*512 + g*8;
  const int* adjR1 = adjR0 + (size_t)16*NN;
  const float* edB = e_dst + b*NN + q*512 + g*8;
  // gll source: lane byte-offset pre-swizzled (involution on bits 4-5)
  const int lsw = ((l*16) ^ (((l>>3)&3)<<4)) >> 1;   // in shorts
  const unsigned short* hTq = hT + (size_t)b*BSLAB + (size_t)q*16*TILE_SH
                                 + (size_t)w*4096 + lsw;
  char* ldsW       = smem + q*16384 + w*8192;    // stage dest (+buf*65536+i*1024)
  const char* ldsR = smem + q*16384;             // read base (+buf*65536)
  // swizzled B-frag read offset within a 1KB o-subtile
  const int hoff = (r16*64 + g*16) ^ (((r16>>1)&3)<<4);
  const float es0 = e_src[b*NN + n0 + w*32 + r16];
  const float es1 = e_src[b*NN + n0 + w*32 + 16 + r16];

  f32x4 acc0[16], acc1[16];
#pragma unroll
  for (int c=0;c<16;c++){ acc0[c] = (f32x4){0.f,0.f,0.f,0.f};
                          acc1[c] = (f32x4){0.f,0.f,0.f,0.f}; }
  float ps0 = 0.f, ps1 = 0.f;

  auto mkp = [&](i32x4 a0, i32x4 a1, float4 e0, float4 e1,
                 float es, float& ps)->short8{
    int   ai[8] = {a0[0],a0[1],a0[2],a0[3],a1[0],a1[1],a1[2],a1[3]};
    float ev[8] = {e0.x,e0.y,e0.z,e0.w,e1.x,e1.y,e1.z,e1.w};
    unsigned pt[8];
#pragma unroll
    for (int j=0;j<8;j++){
      float s = es + ev[j];
      s = fmaxf(s, ALPHA*s);                       // leaky relu
      float p = __expf(s);
      p = (ai[j] > 0) ? p : 0.f;
      unsigned ub = __builtin_bit_cast(unsigned, p) & 0xFFFF0000u;
      ps += __builtin_bit_cast(float, ub);         // rowsum of truncated P
      pt[j] = ub;
    }
    union { short8 v; unsigned u[4]; } A;
#pragma unroll
    for (int j=0;j<4;j++) A.u[j] = pt[2*j+1] | (pt[2*j] >> 16);
    return A.v;
  };

  // ---- prologue: adj(0), e(0), stage tile 0 -> buf0 ----
  i32x4 aj00,aj01, aj10,aj11;
  float4 eC0, eC1;
  {
    const i32x4* p0 = (const i32x4*)adjR0;
    aj00 = __builtin_nontemporal_load(p0);
    aj01 = __builtin_nontemporal_load(p0+1);
    const i32x4* p1 = (const i32x4*)adjR1;
    aj10 = __builtin_nontemporal_load(p1);
    aj11 = __builtin_nontemporal_load(p1+1);
    eC0 = *(const float4*)edB; eC1 = *(const float4*)(edB+4);
  }
#pragma unroll
  for (int i=0;i<8;i++) gll16(hTq + i*512, ldsW + i*1024);

  for (int t = 0; t < 16; ++t){
    const int cur = t & 1, nxt = cur ^ 1;
    const int ts  = (t < 15) ? t+1 : 15;           // stage target (tail dummy)
    // (1) stage tile ts into buf[nxt] : 8 gll16
    {
      const unsigned short* gsrc = hTq + (size_t)ts*TILE_SH;
      char* ld = ldsW + nxt*65536;
#pragma unroll
      for (int i=0;i<8;i++) gll16(gsrc + i*512, ld + i*1024);
    }
    // (2) wait: everything older than this step's 8 gll retired.
    asm volatile("s_waitcnt vmcnt(8)" ::: "memory");
    __builtin_amdgcn_sched_barrier(0);
    __builtin_amdgcn_s_barrier();
    __builtin_amdgcn_sched_barrier(0);
    // (3) softmax fragments for step t (adj/e in regs)
    short8 pa0 = mkp(aj00,aj01, eC0,eC1, es0, ps0);
    short8 pa1 = mkp(aj10,aj11, eC0,eC1, es1, ps1);
    // (4) refill adj/e for t+1 (fly across the end barrier)
    const int tn = (t < 15) ? t+1 : 0;
    {
      const i32x4* p0 = (const i32x4*)(adjR0 + tn*32);
      aj00 = __builtin_nontemporal_load(p0);
      aj01 = __builtin_nontemporal_load(p0+1);
      const i32x4* p1 = (const i32x4*)(adjR1 + tn*32);
      aj10 = __builtin_nontemporal_load(p1);
      aj11 = __builtin_nontemporal_load(p1+1);
      const float* ep = edB + tn*32;
      eC0 = *(const float4*)ep; eC1 = *(const float4*)(ep+4);
    }
    // (5) ds_read (swizzled) + MFMA
    {
      const char* rb = ldsR + cur*65536;
      __builtin_amdgcn_s_setprio(1);
#pragma unroll
      for (int c=0;c<16;c++){
        int4 bv = *(const int4*)(rb + c*1024 + hoff);
        acc0[c] = __builtin_amdgcn_mfma_f32_16x16x32_bf16(
                    pa0, __builtin_bit_cast(short8, bv), acc0[c], 0, 0, 0);
        acc1[c] = __builtin_amdgcn_mfma_f32_16x16x32_bf16(
                    pa1, __builtin_bit_cast(short8, bv), acc1[c], 0, 0, 0);
      }
      __builtin_amdgcn_s_setprio(0);
    }
    // (6) end barrier: protects buf[cur] from next step's staging (WAR)
    __builtin_amdgcn_sched_barrier(0);
    __builtin_amdgcn_s_barrier();
    __builtin_amdgcn_sched_barrier(0);
  }
  asm volatile("" :: "v"(aj00[0]),"v"(aj10[0]),"v"(eC0.x),"v"(eC1.x));

  // ---- partial rowsums ----
  float rs0 = ps0, rs1 = ps1;
  rs0 += __shfl_xor(rs0, 16); rs0 += __shfl_xor(rs0, 32);
  rs1 += __shfl_xor(rs1, 16); rs1 += __shfl_xor(rs1, 32);
  if (l < 16){ rsum[w*2][q][l] = rs0; rsum[w*2+1][q][l] = rs1; }
  __syncthreads();

  float t0 = rsum[w*2  ][0][r16] + rsum[w*2  ][1][r16]
           + rsum[w*2  ][2][r16] + rsum[w*2  ][3][r16];
  float t1 = rsum[w*2+1][0][r16] + rsum[w*2+1][1][r16]
           + rsum[w*2+1][2][r16] + rsum[w*2+1][3][r16];
  float inv0[4], inv1[4];
#pragma unroll
  for (int r=0;r<4;r++){ inv0[r] = 1.0f / __shfl(t0, g*4 + r);
                         inv1[r] = 1.0f / __shfl(t1, g*4 + r); }

  // ---- 2 combine rounds (full tile per round), red on staging LDS ----
  f32x4* red = (f32x4*)smem;                       // [w][c16][q][l]
#define RED(W_,C_,Q_,L_) red[(((W_)*16 + (C_))*4 + (Q_))*64 + (L_)]
#pragma unroll
  for (int s = 0; s < 2; ++s){
    f32x4* accp = s ? acc1 : acc0;
#pragma unroll
    for (int c=0;c<16;c++) RED(w,c,q,l) = accp[c];
    __syncthreads();
    const float* inv_ = s ? inv1 : inv0;
    float* outB = out + (size_t)(b*NN + n0 + w*32 + s*16)*FD;
#pragma unroll
    for (int i=0;i<4;i++){
      const int c = q*4 + i;
      f32x4 v = RED(w,c,0,l) + RED(w,c,1,l) + RED(w,c,2,l) + RED(w,c,3,l);
#pragma unroll
      for (int r=0;r<4;r++){
        float o = v[r] * inv_[r];
        o = o > 0.f ? o : (__expf(o) - 1.f);       // ELU
        __builtin_nontemporal_store(o,
            &outB[(size_t)(g*4 + r)*FD + c*16 + r16]);
      }
    }
    __syncthreads();
  }
#undef RED
}

// ---------------------------------------------------------------------------
extern "C" void kernel_launch(void* const* d_in, const int* in_sizes, int n_in,
                              void* d_out, int out_size, void* d_ws, size_t ws_size,
                              hipStream_t stream)
{
  const float* x   = (const float*)d_in[0];
  const int*   adj = (const int*)  d_in[1];
  const float* W   = (const float*)d_in[2];
  const float* a   = (const float*)d_in[3];
  float* out = (float*)d_out;

  char* ws = (char*)d_ws;
  size_t off = 0;
  auto alloc = [&](size_t bytes)->char*{
    char* p = ws + off; off += (bytes + 255) & ~(size_t)255; return p;
  };
  unsigned short* WT    = (unsigned short*)alloc((size_t)FD*FD*2);
  float*          w_src = (float*)alloc(FD*4);
  float*          w_dst = (float*)alloc(FD*4);
  float*          e_src = (float*)alloc((size_t)BATCH*NN*4);
  float*          e_dst = (float*)alloc((size_t)BATCH*NN*4);
  unsigned short* hT    = (unsigned short*)alloc((size_t)BATCH*NN*FD*2);

  prep_w   <<<FD,              64,  0, stream>>>(W, a, w_src, w_dst, WT);
  gemm_he  <<<(BATCH*NN)/64,   256, 0, stream>>>(x, w_src, w_dst, WT, hT, e_src, e_dst);
  gat_fused<<<(BATCH*NN)/64,   512, 0, stream>>>(adj, e_src, e_dst, hT, out);
}